// Round 11
// baseline (632.793 us; speedup 1.0000x reference)
//
#include <hip/hip_runtime.h>

#define NN 50000
#define NE 600000
#define LAT 128
#define IN_F 7
#define CSR_W 64   // padded CSR capacity; Poisson(12) -> P(deg>63) ~ 0
#define HSTR 136   // LDS row stride (bf16 elems)
#define NRANGE 32            // range-owner build blocks
#define RNGSZ ((NN + NRANGE - 1) / NRANGE)   // 1563 nodes per range

typedef __attribute__((ext_vector_type(8))) short bfrag;   // 8 bf16 = 4 VGPRs
typedef __attribute__((ext_vector_type(4))) float ffrag;   // 4 fp32 acc
typedef __attribute__((ext_vector_type(2))) float f32x2;

__device__ inline unsigned short f2bf(float f) {
    unsigned int u = __float_as_uint(f);
    return (unsigned short)((u + 0x7FFFu + ((u >> 16) & 1u)) >> 16);
}
__device__ inline float bf2f(unsigned int b) { return __uint_as_float(b << 16); }

// ---------------- prep: pack 6 weight mats to B-frag bf16 (no cnt zeroing needed) ----------------

__global__ void k_prep(const float* __restrict__ W, unsigned short* __restrict__ Wp) {
    int t = blockIdx.x * 256 + threadIdx.x;
    if (t >= 6 * 8 * 4 * 64) return;
    int lane = t & 63;
    int ks = (t >> 6) & 3;
    int nt = (t >> 8) & 7;
    int mat = t >> 11;
    int n = nt * 16 + (lane & 15);
    int k0 = ks * 32 + (lane >> 4) * 8;
    const float* src = W + (size_t)mat * LAT * LAT;
    unsigned long long lo = 0, hi = 0;
#pragma unroll
    for (int j = 0; j < 4; ++j)
        lo |= (unsigned long long)f2bf(src[(k0 + j) * LAT + n]) << (16 * j);
#pragma unroll
    for (int j = 0; j < 4; ++j)
        hi |= (unsigned long long)f2bf(src[(k0 + 4 + j) * LAT + n]) << (16 * j);
    unsigned long long* dst = (unsigned long long*)(Wp + (size_t)t * 8);
    dst[0] = lo; dst[1] = hi;
}

// ---------------- fused: [range-owner CSR build (LDS atomics) | embed+MLP-step1] ----------------
// Build: NRANGE blocks; block g owns nodes [g*RNGSZ, (g+1)*RNGSZ). It streams
// the full edge list (int4-vectorized) and does histogram + cursor in LDS —
// ZERO global atomics. Slot region is single-writer; cnt written coalesced once.
// x (fp8 e4m3) is UNSCALED (inv_s applied in agg mode 0).

__global__ __launch_bounds__(256) void k_fused1(
    const int* __restrict__ s, const int* __restrict__ r,
    unsigned int* __restrict__ cnt, unsigned short* __restrict__ slot,
    const float* __restrict__ nodes, const float* __restrict__ We,
    const float* __restrict__ be,
    const unsigned short* __restrict__ W0p, const unsigned short* __restrict__ W1p,
    const float* __restrict__ b0, const float* __restrict__ b1,
    unsigned char* __restrict__ x, int build_blocks)
{
    __shared__ unsigned short hs[64][HSTR];   // 17.4 KB; build path reuses as uint[RNGSZ]
    int tid = threadIdx.x;

    if ((int)blockIdx.x < build_blocks) {
        unsigned int* lcnt = (unsigned int*)hs;       // 6.3 KB of the 17.4 KB
        int rlo = (int)blockIdx.x * RNGSZ;
        int rhi = rlo + RNGSZ; if (rhi > NN) rhi = NN;
        int n = rhi - rlo;
        for (int i = tid; i < n; i += 256) lcnt[i] = 0;
        __syncthreads();

        const int4* s4 = (const int4*)s;
        const int4* r4 = (const int4*)r;
        for (int i = tid; i < NE / 4; i += 256) {
            int4 sv = s4[i];
            int4 rv = r4[i];
#pragma unroll
            for (int j = 0; j < 4; ++j) {
                int ss = (&sv.x)[j], rr = (&rv.x)[j];
                if (ss >= rlo && ss < rhi)
                    atomicAdd(&lcnt[ss - rlo], 1u);
                if (rr >= rlo && rr < rhi) {
                    unsigned int p = atomicAdd(&lcnt[rr - rlo], 0x10000u) >> 16;
                    if (p < CSR_W) slot[(size_t)rr * CSR_W + p] = (unsigned short)ss;
                }
            }
        }
        __syncthreads();
        for (int i = tid; i < n; i += 256) cnt[rlo + i] = lcnt[i];
        return;
    }

    int brow = ((int)blockIdx.x - build_blocks) * 64;
    int rows = NN - brow; if (rows > 64) rows = 64;

    // embed directly into LDS (h never materialized in HBM)
#pragma unroll
    for (int it = 0; it < 8; ++it) {
        int fi = it * 256 + tid;
        int rr = fi >> 5, cc = (fi & 31) << 2;
        if (rr < rows) {
            const float* nr = nodes + (size_t)(brow + rr) * IN_F;
            float o0 = be[cc], o1 = be[cc + 1], o2 = be[cc + 2], o3 = be[cc + 3];
#pragma unroll
            for (int k = 0; k < IN_F; ++k) {
                float nv = nr[k];
                const float* wk = We + k * LAT + cc;
                o0 += nv * wk[0]; o1 += nv * wk[1];
                o2 += nv * wk[2]; o3 += nv * wk[3];
            }
            unsigned long long pk = (unsigned long long)f2bf(o0)
                | ((unsigned long long)f2bf(o1) << 16)
                | ((unsigned long long)f2bf(o2) << 32)
                | ((unsigned long long)f2bf(o3) << 48);
            *(unsigned long long*)&hs[rr][cc] = pk;
        }
    }
    __syncthreads();

    int w = tid >> 6, lane = tid & 63;
    int mrow = w * 16 + (lane & 15);
    int koff = (lane >> 4) * 8;
    int ccol = lane & 15;
    int crow = w * 16 + (lane >> 4) * 4;

    float bia0[8], bia1[8];
#pragma unroll
    for (int nt = 0; nt < 8; ++nt) { bia0[nt] = b0[nt * 16 + ccol]; bia1[nt] = b1[nt * 16 + ccol]; }

    ffrag acc[8];
#pragma unroll
    for (int nt = 0; nt < 8; ++nt) acc[nt] = (ffrag)0.0f;
#pragma unroll
    for (int ks = 0; ks < 4; ++ks) {
        bfrag af = *(const bfrag*)&hs[mrow][ks * 32 + koff];
#pragma unroll
        for (int nt = 0; nt < 8; ++nt) {
            bfrag bf = *(const bfrag*)&W0p[(size_t)(((nt * 4) + ks) * 64 + lane) * 8];
            acc[nt] = __builtin_amdgcn_mfma_f32_16x16x32_bf16(af, bf, acc[nt], 0, 0, 0);
        }
    }
#pragma unroll
    for (int nt = 0; nt < 8; ++nt)
#pragma unroll
        for (int reg = 0; reg < 4; ++reg)
            hs[crow + reg][nt * 16 + ccol] = f2bf(fmaxf(acc[nt][reg] + bia0[nt], 0.f));
    __syncthreads();

#pragma unroll
    for (int nt = 0; nt < 8; ++nt) acc[nt] = (ffrag)0.0f;
#pragma unroll
    for (int ks = 0; ks < 4; ++ks) {
        bfrag af = *(const bfrag*)&hs[mrow][ks * 32 + koff];
#pragma unroll
        for (int nt = 0; nt < 8; ++nt) {
            bfrag bf = *(const bfrag*)&W1p[(size_t)(((nt * 4) + ks) * 64 + lane) * 8];
            acc[nt] = __builtin_amdgcn_mfma_f32_16x16x32_bf16(af, bf, acc[nt], 0, 0, 0);
        }
    }
    __syncthreads();
#pragma unroll
    for (int nt = 0; nt < 8; ++nt)
#pragma unroll
        for (int reg = 0; reg < 4; ++reg)
            hs[crow + reg][nt * 16 + ccol] = f2bf(fmaxf(acc[nt][reg] + bia1[nt], 0.f));
    __syncthreads();

    // copy-out with bf16 -> fp8 e4m3 conversion (row = 128 B)
#pragma unroll
    for (int it = 0; it < 8; ++it) {
        int fi = it * 256 + tid;            // uint index: 32 per row
        int rr = fi >> 5, uc = fi & 31;
        if (rr < rows) {
            unsigned long long pk8 = *(unsigned long long*)&hs[rr][uc * 4];
            float f0 = bf2f((unsigned int)(pk8 & 0xFFFFu));
            float f1 = bf2f((unsigned int)((pk8 >> 16) & 0xFFFFu));
            float f2 = bf2f((unsigned int)((pk8 >> 32) & 0xFFFFu));
            float f3 = bf2f((unsigned int)((pk8 >> 48) & 0xFFFFu));
            int o = __builtin_amdgcn_cvt_pk_fp8_f32(f0, f1, 0, false);
            o = __builtin_amdgcn_cvt_pk_fp8_f32(f2, f3, o, true);
            *(int*)&x[(size_t)(brow + rr) * LAT + uc * 4] = o;
        }
    }
}

// ---------------- MLP steps 2,3 — inv_sqrt(sender_deg) in epilogue, fp8 x out ----------------

__global__ __launch_bounds__(256) void k_mlp2(
    const unsigned short* __restrict__ h,
    const unsigned short* __restrict__ W0p, const unsigned short* __restrict__ W1p,
    const float* __restrict__ b0, const float* __restrict__ b1,
    const unsigned int* __restrict__ cnt,
    unsigned char* __restrict__ x, int M)
{
    __shared__ unsigned short hs[64][HSTR];
    int brow = blockIdx.x * 64;
    int tid = threadIdx.x;
    int rows = M - brow; if (rows > 64) rows = 64;

#pragma unroll
    for (int it = 0; it < 8; ++it) {
        int fi = it * 256 + tid;
        int rr = fi >> 5, cc = (fi & 31) << 2;
        if (rr < rows)
            *(unsigned long long*)&hs[rr][cc] =
                *(const unsigned long long*)&h[(size_t)(brow + rr) * LAT + cc];
    }
    __syncthreads();

    int w = tid >> 6, lane = tid & 63;
    int mrow = w * 16 + (lane & 15);
    int koff = (lane >> 4) * 8;
    int ccol = lane & 15;
    int crow = w * 16 + (lane >> 4) * 4;

    float bia0[8], bia1[8];
#pragma unroll
    for (int nt = 0; nt < 8; ++nt) { bia0[nt] = b0[nt * 16 + ccol]; bia1[nt] = b1[nt * 16 + ccol]; }
    float iv[4];
#pragma unroll
    for (int reg = 0; reg < 4; ++reg) {
        int rw = brow + crow + reg;
        unsigned int ds = cnt[rw < NN ? rw : NN - 1] & 0xFFFFu;
        iv[reg] = rsqrtf((float)(ds > 1 ? ds : 1));
    }

    ffrag acc[8];
#pragma unroll
    for (int nt = 0; nt < 8; ++nt) acc[nt] = (ffrag)0.0f;
#pragma unroll
    for (int ks = 0; ks < 4; ++ks) {
        bfrag af = *(const bfrag*)&hs[mrow][ks * 32 + koff];
#pragma unroll
        for (int nt = 0; nt < 8; ++nt) {
            bfrag bf = *(const bfrag*)&W0p[(size_t)(((nt * 4) + ks) * 64 + lane) * 8];
            acc[nt] = __builtin_amdgcn_mfma_f32_16x16x32_bf16(af, bf, acc[nt], 0, 0, 0);
        }
    }
#pragma unroll
    for (int nt = 0; nt < 8; ++nt)
#pragma unroll
        for (int reg = 0; reg < 4; ++reg)
            hs[crow + reg][nt * 16 + ccol] = f2bf(fmaxf(acc[nt][reg] + bia0[nt], 0.f));
    __syncthreads();

#pragma unroll
    for (int nt = 0; nt < 8; ++nt) acc[nt] = (ffrag)0.0f;
#pragma unroll
    for (int ks = 0; ks < 4; ++ks) {
        bfrag af = *(const bfrag*)&hs[mrow][ks * 32 + koff];
#pragma unroll
        for (int nt = 0; nt < 8; ++nt) {
            bfrag bf = *(const bfrag*)&W1p[(size_t)(((nt * 4) + ks) * 64 + lane) * 8];
            acc[nt] = __builtin_amdgcn_mfma_f32_16x16x32_bf16(af, bf, acc[nt], 0, 0, 0);
        }
    }
    __syncthreads();
#pragma unroll
    for (int nt = 0; nt < 8; ++nt)
#pragma unroll
        for (int reg = 0; reg < 4; ++reg)
            hs[crow + reg][nt * 16 + ccol] =
                f2bf(fmaxf(acc[nt][reg] + bia1[nt], 0.f) * iv[reg]);
    __syncthreads();

#pragma unroll
    for (int it = 0; it < 8; ++it) {
        int fi = it * 256 + tid;
        int rr = fi >> 5, uc = fi & 31;
        if (rr < rows) {
            unsigned long long pk8 = *(unsigned long long*)&hs[rr][uc * 4];
            float f0 = bf2f((unsigned int)(pk8 & 0xFFFFu));
            float f1 = bf2f((unsigned int)((pk8 >> 16) & 0xFFFFu));
            float f2 = bf2f((unsigned int)((pk8 >> 32) & 0xFFFFu));
            float f3 = bf2f((unsigned int)((pk8 >> 48) & 0xFFFFu));
            int o = __builtin_amdgcn_cvt_pk_fp8_f32(f0, f1, 0, false);
            o = __builtin_amdgcn_cvt_pk_fp8_f32(f2, f3, o, true);
            *(int*)&x[(size_t)(brow + rr) * LAT + uc * 4] = o;
        }
    }
}

// ---------------- aggregate + skip + LayerNorm (+ fused decode) — R8-proven ----------------
// Wave-per-node; 8-way ILP gather of fp8 rows (2 B/lane coalesced, HW convert).
// mode 0: x unscaled -> per-edge inv_s weight via shfl; skip = inline embed.
// mode 1: x pre-scaled by mlp2; skip = h row.
// mode 2: as 1, plus fused decode to outd.

__global__ __launch_bounds__(256) void k_agg(
    const unsigned char* __restrict__ x, unsigned short* __restrict__ h,
    const float* __restrict__ nodes, const float* __restrict__ We,
    const float* __restrict__ be,
    const unsigned int* __restrict__ cnt, const unsigned short* __restrict__ slot,
    const float* __restrict__ gamma, const float* __restrict__ beta,
    const float* __restrict__ Wd, const float* __restrict__ bd,
    float* __restrict__ outd, int mode)
{
    int lane = threadIdx.x & 63;
    int r = blockIdx.x * 4 + (threadIdx.x >> 6);
    if (r >= NN) return;

    int ct = (int)(cnt[r] >> 16);
    float ir = rsqrtf((float)(ct > 1 ? ct : 1));
    int c = ct > CSR_W ? CSR_W : ct;

    int myidx = (lane < c) ? (int)slot[(size_t)r * CSR_W + lane] : 0;

    int j0 = lane * 2;   // channel pair == byte offset in fp8 row
    float ax0 = 0.f, ay0 = 0.f, ax1 = 0.f, ay1 = 0.f;
    float ax2 = 0.f, ay2 = 0.f, ax3 = 0.f, ay3 = 0.f;
    float ax4 = 0.f, ay4 = 0.f, ax5 = 0.f, ay5 = 0.f;
    float ax6 = 0.f, ay6 = 0.f, ax7 = 0.f, ay7 = 0.f;
    int e = 0;

    if (mode == 0) {
        float myinv = 0.f;
        if (lane < c) {
            unsigned int ds = cnt[myidx] & 0xFFFFu;
            myinv = rsqrtf((float)(ds > 1 ? ds : 1));
        }
        for (; e + 8 <= c; e += 8) {
            int s0 = __shfl(myidx, e),     s1 = __shfl(myidx, e + 1);
            int s2 = __shfl(myidx, e + 2), s3 = __shfl(myidx, e + 3);
            int s4 = __shfl(myidx, e + 4), s5 = __shfl(myidx, e + 5);
            int s6 = __shfl(myidx, e + 6), s7 = __shfl(myidx, e + 7);
            float w0 = __shfl(myinv, e),     w1 = __shfl(myinv, e + 1);
            float w2 = __shfl(myinv, e + 2), w3 = __shfl(myinv, e + 3);
            float w4 = __shfl(myinv, e + 4), w5 = __shfl(myinv, e + 5);
            float w6 = __shfl(myinv, e + 6), w7 = __shfl(myinv, e + 7);
            unsigned short v0 = *(const unsigned short*)&x[(size_t)s0 * LAT + j0];
            unsigned short v1 = *(const unsigned short*)&x[(size_t)s1 * LAT + j0];
            unsigned short v2 = *(const unsigned short*)&x[(size_t)s2 * LAT + j0];
            unsigned short v3 = *(const unsigned short*)&x[(size_t)s3 * LAT + j0];
            unsigned short v4 = *(const unsigned short*)&x[(size_t)s4 * LAT + j0];
            unsigned short v5 = *(const unsigned short*)&x[(size_t)s5 * LAT + j0];
            unsigned short v6 = *(const unsigned short*)&x[(size_t)s6 * LAT + j0];
            unsigned short v7 = *(const unsigned short*)&x[(size_t)s7 * LAT + j0];
            f32x2 d0 = __builtin_amdgcn_cvt_pk_f32_fp8((int)v0, false);
            f32x2 d1 = __builtin_amdgcn_cvt_pk_f32_fp8((int)v1, false);
            f32x2 d2 = __builtin_amdgcn_cvt_pk_f32_fp8((int)v2, false);
            f32x2 d3 = __builtin_amdgcn_cvt_pk_f32_fp8((int)v3, false);
            f32x2 d4 = __builtin_amdgcn_cvt_pk_f32_fp8((int)v4, false);
            f32x2 d5 = __builtin_amdgcn_cvt_pk_f32_fp8((int)v5, false);
            f32x2 d6 = __builtin_amdgcn_cvt_pk_f32_fp8((int)v6, false);
            f32x2 d7 = __builtin_amdgcn_cvt_pk_f32_fp8((int)v7, false);
            ax0 += d0.x * w0; ay0 += d0.y * w0;
            ax1 += d1.x * w1; ay1 += d1.y * w1;
            ax2 += d2.x * w2; ay2 += d2.y * w2;
            ax3 += d3.x * w3; ay3 += d3.y * w3;
            ax4 += d4.x * w4; ay4 += d4.y * w4;
            ax5 += d5.x * w5; ay5 += d5.y * w5;
            ax6 += d6.x * w6; ay6 += d6.y * w6;
            ax7 += d7.x * w7; ay7 += d7.y * w7;
        }
        for (; e < c; ++e) {
            int s0 = __shfl(myidx, e);
            float w0 = __shfl(myinv, e);
            unsigned short v0 = *(const unsigned short*)&x[(size_t)s0 * LAT + j0];
            f32x2 d0 = __builtin_amdgcn_cvt_pk_f32_fp8((int)v0, false);
            ax0 += d0.x * w0; ay0 += d0.y * w0;
        }
    } else {
        for (; e + 8 <= c; e += 8) {
            int s0 = __shfl(myidx, e),     s1 = __shfl(myidx, e + 1);
            int s2 = __shfl(myidx, e + 2), s3 = __shfl(myidx, e + 3);
            int s4 = __shfl(myidx, e + 4), s5 = __shfl(myidx, e + 5);
            int s6 = __shfl(myidx, e + 6), s7 = __shfl(myidx, e + 7);
            unsigned short v0 = *(const unsigned short*)&x[(size_t)s0 * LAT + j0];
            unsigned short v1 = *(const unsigned short*)&x[(size_t)s1 * LAT + j0];
            unsigned short v2 = *(const unsigned short*)&x[(size_t)s2 * LAT + j0];
            unsigned short v3 = *(const unsigned short*)&x[(size_t)s3 * LAT + j0];
            unsigned short v4 = *(const unsigned short*)&x[(size_t)s4 * LAT + j0];
            unsigned short v5 = *(const unsigned short*)&x[(size_t)s5 * LAT + j0];
            unsigned short v6 = *(const unsigned short*)&x[(size_t)s6 * LAT + j0];
            unsigned short v7 = *(const unsigned short*)&x[(size_t)s7 * LAT + j0];
            f32x2 d0 = __builtin_amdgcn_cvt_pk_f32_fp8((int)v0, false);
            f32x2 d1 = __builtin_amdgcn_cvt_pk_f32_fp8((int)v1, false);
            f32x2 d2 = __builtin_amdgcn_cvt_pk_f32_fp8((int)v2, false);
            f32x2 d3 = __builtin_amdgcn_cvt_pk_f32_fp8((int)v3, false);
            f32x2 d4 = __builtin_amdgcn_cvt_pk_f32_fp8((int)v4, false);
            f32x2 d5 = __builtin_amdgcn_cvt_pk_f32_fp8((int)v5, false);
            f32x2 d6 = __builtin_amdgcn_cvt_pk_f32_fp8((int)v6, false);
            f32x2 d7 = __builtin_amdgcn_cvt_pk_f32_fp8((int)v7, false);
            ax0 += d0.x; ay0 += d0.y;  ax1 += d1.x; ay1 += d1.y;
            ax2 += d2.x; ay2 += d2.y;  ax3 += d3.x; ay3 += d3.y;
            ax4 += d4.x; ay4 += d4.y;  ax5 += d5.x; ay5 += d5.y;
            ax6 += d6.x; ay6 += d6.y;  ax7 += d7.x; ay7 += d7.y;
        }
        for (; e < c; ++e) {
            int s0 = __shfl(myidx, e);
            unsigned short v0 = *(const unsigned short*)&x[(size_t)s0 * LAT + j0];
            f32x2 d0 = __builtin_amdgcn_cvt_pk_f32_fp8((int)v0, false);
            ax0 += d0.x; ay0 += d0.y;
        }
    }

    float a0 = (((ax0 + ax1) + (ax2 + ax3)) + ((ax4 + ax5) + (ax6 + ax7))) * ir;
    float a1 = (((ay0 + ay1) + (ay2 + ay3)) + ((ay4 + ay5) + (ay6 + ay7))) * ir;

    float v0, v1;
    if (mode == 0) {
        float o0 = be[j0], o1 = be[j0 + 1];
#pragma unroll
        for (int k = 0; k < IN_F; ++k) {
            float nv = nodes[(size_t)r * IN_F + k];
            o0 += nv * We[k * LAT + j0];
            o1 += nv * We[k * LAT + j0 + 1];
        }
        v0 = o0 + a0; v1 = o1 + a1;
    } else {
        unsigned int hv = *(const unsigned int*)&h[(size_t)r * LAT + j0];
        v0 = bf2f(hv & 0xFFFFu) + a0;
        v1 = bf2f(hv >> 16) + a1;
    }

    float sum = v0 + v1, sq = v0 * v0 + v1 * v1;
#pragma unroll
    for (int m = 1; m <= 32; m <<= 1) {
        sum += __shfl_xor(sum, m);
        sq  += __shfl_xor(sq, m);
    }
    float mu = sum * (1.f / LAT);
    float rs = rsqrtf(sq * (1.f / LAT) - mu * mu + 1e-6f);

    float o0 = (v0 - mu) * rs * gamma[j0] + beta[j0];
    float o1 = (v1 - mu) * rs * gamma[j0 + 1] + beta[j0 + 1];

    if (mode < 2) {
        *(unsigned int*)&h[(size_t)r * LAT + j0] =
            (unsigned int)f2bf(o0) | ((unsigned int)f2bf(o1) << 16);
    } else {
        const float* wd0 = Wd + j0 * IN_F;
        const float* wd1 = Wd + (j0 + 1) * IN_F;
#pragma unroll
        for (int f = 0; f < IN_F; ++f) {
            float pv = o0 * wd0[f] + o1 * wd1[f];
#pragma unroll
            for (int m = 1; m <= 32; m <<= 1) pv += __shfl_xor(pv, m);
            if (lane == 0) outd[(size_t)r * IN_F + f] = pv + bd[f];
        }
    }
}

// ---------------- host ----------------

extern "C" void kernel_launch(void* const* d_in, const int* in_sizes, int n_in,
                              void* d_out, int out_size, void* d_ws, size_t ws_size,
                              hipStream_t stream)
{
    const float* nodes   = (const float*)d_in[0];
    const int*   senders = (const int*)d_in[1];
    const int*   recvs   = (const int*)d_in[2];
    const float* W_embed = (const float*)d_in[3];
    const float* b_embed = (const float*)d_in[4];
    const float* mlp_W   = (const float*)d_in[5];
    const float* mlp_b   = (const float*)d_in[6];
    const float* ln_s    = (const float*)d_in[7];
    const float* ln_b    = (const float*)d_in[8];
    const float* W_dec   = (const float*)d_in[9];
    const float* b_dec   = (const float*)d_in[10];
    float* out = (float*)d_out;

    char* p = (char*)d_ws;
    auto alloc = [&](size_t bytes) -> char* {
        char* q = p; p += (bytes + 255) & ~(size_t)255; return q;
    };
    unsigned short* h    = (unsigned short*)alloc((size_t)NN * LAT * 2);
    unsigned char*  x    = (unsigned char*)alloc((size_t)NN * LAT);
    unsigned short* Wp   = (unsigned short*)alloc((size_t)6 * LAT * LAT * 2);
    unsigned int* cnt    = (unsigned int*)alloc((size_t)NN * 4);
    unsigned short* slot = (unsigned short*)alloc((size_t)NN * CSR_W * 2);

    k_prep<<<(6 * 8 * 4 * 64 + 255) / 256, 256, 0, stream>>>(mlp_W, Wp);

    int build_blocks = NRANGE;                           // 32 range-owner blocks
    int mlp_blocks   = (NN + 63) / 64;                   // 782
    int agg_blocks   = (NN + 3) / 4;                     // 12500

    const float* b0 = mlp_b;
    k_fused1<<<build_blocks + mlp_blocks, 256, 0, stream>>>(
        senders, recvs, cnt, slot, nodes, W_embed, b_embed,
        Wp, Wp + (size_t)LAT * LAT, b0, b0 + LAT, x, build_blocks);

    // step 1 (x unscaled -> weighted gather; skip = inline embed)
    k_agg<<<agg_blocks, 256, 0, stream>>>(
        x, h, nodes, W_embed, b_embed, cnt, slot,
        ln_s, ln_b, nullptr, nullptr, nullptr, 0);

    // step 2
    k_mlp2<<<mlp_blocks, 256, 0, stream>>>(
        h, Wp + (size_t)2 * LAT * LAT, Wp + (size_t)3 * LAT * LAT,
        b0 + 2 * LAT, b0 + 3 * LAT, cnt, x, NN);
    k_agg<<<agg_blocks, 256, 0, stream>>>(
        x, h, nodes, W_embed, b_embed, cnt, slot,
        ln_s + LAT, ln_b + LAT, nullptr, nullptr, nullptr, 1);

    // step 3 (+ fused decode)
    k_mlp2<<<mlp_blocks, 256, 0, stream>>>(
        h, Wp + (size_t)4 * LAT * LAT, Wp + (size_t)5 * LAT * LAT,
        b0 + 4 * LAT, b0 + 5 * LAT, cnt, x, NN);
    k_agg<<<agg_blocks, 256, 0, stream>>>(
        x, h, nodes, W_embed, b_embed, cnt, slot,
        ln_s + 2 * LAT, ln_b + 2 * LAT, W_dec, b_dec, out, 2);
}

// Round 12
// 293.998 us; speedup vs baseline: 2.1524x; 2.1524x over previous
//
#include <hip/hip_runtime.h>

#define NN 50000
#define NE 600000
#define LAT 128
#define IN_F 7
#define CSR_W 64   // padded CSR capacity; Poisson(12) -> P(deg>63) ~ 0
#define HSTR 136   // LDS row stride (bf16 elems)
#define NXCD 8     // build partition count (XCD heuristic: blockIdx % 8)
#define RNG (NN / NXCD)   // 6250 per range

typedef __attribute__((ext_vector_type(8))) short bfrag;   // 8 bf16 = 4 VGPRs
typedef __attribute__((ext_vector_type(4))) float ffrag;   // 4 fp32 acc
typedef __attribute__((ext_vector_type(2))) float f32x2;

__device__ inline unsigned short f2bf(float f) {
    unsigned int u = __float_as_uint(f);
    return (unsigned short)((u + 0x7FFFu + ((u >> 16) & 1u)) >> 16);
}
__device__ inline float bf2f(unsigned int b) { return __uint_as_float(b << 16); }

// ---------------- prep: zero cnt + pack 6 weight mats to B-frag bf16 ----------------

__global__ void k_prep(const float* __restrict__ W, unsigned short* __restrict__ Wp,
                       unsigned int* __restrict__ cnt) {
    int t = blockIdx.x * 256 + threadIdx.x;
    if (t < NN) cnt[t] = 0;
    if (t < 6 * 8 * 4 * 64) {
        int lane = t & 63;
        int ks = (t >> 6) & 3;
        int nt = (t >> 8) & 7;
        int mat = t >> 11;
        int n = nt * 16 + (lane & 15);
        int k0 = ks * 32 + (lane >> 4) * 8;
        const float* src = W + (size_t)mat * LAT * LAT;
        unsigned long long lo = 0, hi = 0;
#pragma unroll
        for (int j = 0; j < 4; ++j)
            lo |= (unsigned long long)f2bf(src[(k0 + j) * LAT + n]) << (16 * j);
#pragma unroll
        for (int j = 0; j < 4; ++j)
            hi |= (unsigned long long)f2bf(src[(k0 + 4 + j) * LAT + n]) << (16 * j);
        unsigned long long* dst = (unsigned long long*)(Wp + (size_t)t * 8);
        dst[0] = lo; dst[1] = hi;
    }
}

// ---------------- fused: [XCD-partitioned CSR build | embed+MLP-step1] — R10-proven ----------------

__global__ __launch_bounds__(256) void k_fused1(
    const int* __restrict__ s, const int* __restrict__ r,
    unsigned int* __restrict__ cnt, unsigned short* __restrict__ slot,
    const float* __restrict__ nodes, const float* __restrict__ We,
    const float* __restrict__ be,
    const unsigned short* __restrict__ W0p, const unsigned short* __restrict__ W1p,
    const float* __restrict__ b0, const float* __restrict__ b1,
    unsigned char* __restrict__ x, int build_blocks)
{
    __shared__ unsigned short hs[64][HSTR];   // 17.4 KB, single buffer
    int tid = threadIdx.x;

    if ((int)blockIdx.x < build_blocks) {
        int g = blockIdx.x & (NXCD - 1);          // XCD heuristic (%8 dispatch)
        int stripe = blockIdx.x >> 3;
        int i = stripe * 256 + tid;
        if (i < NE) {
            int ss = s[i], rr = r[i];
            int rlo = g * RNG;
            if (ss >= rlo && ss < rlo + RNG)
                atomicAdd(&cnt[ss], 1u);
            if (rr >= rlo && rr < rlo + RNG) {
                unsigned int p = atomicAdd(&cnt[rr], 0x10000u) >> 16;
                if (p < CSR_W) slot[(size_t)rr * CSR_W + p] = (unsigned short)ss;
            }
        }
        return;
    }

    int brow = ((int)blockIdx.x - build_blocks) * 64;
    int rows = NN - brow; if (rows > 64) rows = 64;

    // embed directly into LDS (h never materialized in HBM)
#pragma unroll
    for (int it = 0; it < 8; ++it) {
        int fi = it * 256 + tid;
        int rr = fi >> 5, cc = (fi & 31) << 2;
        if (rr < rows) {
            const float* nr = nodes + (size_t)(brow + rr) * IN_F;
            float o0 = be[cc], o1 = be[cc + 1], o2 = be[cc + 2], o3 = be[cc + 3];
#pragma unroll
            for (int k = 0; k < IN_F; ++k) {
                float nv = nr[k];
                const float* wk = We + k * LAT + cc;
                o0 += nv * wk[0]; o1 += nv * wk[1];
                o2 += nv * wk[2]; o3 += nv * wk[3];
            }
            unsigned long long pk = (unsigned long long)f2bf(o0)
                | ((unsigned long long)f2bf(o1) << 16)
                | ((unsigned long long)f2bf(o2) << 32)
                | ((unsigned long long)f2bf(o3) << 48);
            *(unsigned long long*)&hs[rr][cc] = pk;
        }
    }
    __syncthreads();

    int w = tid >> 6, lane = tid & 63;
    int mrow = w * 16 + (lane & 15);
    int koff = (lane >> 4) * 8;
    int ccol = lane & 15;
    int crow = w * 16 + (lane >> 4) * 4;

    float bia0[8], bia1[8];
#pragma unroll
    for (int nt = 0; nt < 8; ++nt) { bia0[nt] = b0[nt * 16 + ccol]; bia1[nt] = b1[nt * 16 + ccol]; }

    ffrag acc[8];
#pragma unroll
    for (int nt = 0; nt < 8; ++nt) acc[nt] = (ffrag)0.0f;
#pragma unroll
    for (int ks = 0; ks < 4; ++ks) {
        bfrag af = *(const bfrag*)&hs[mrow][ks * 32 + koff];
#pragma unroll
        for (int nt = 0; nt < 8; ++nt) {
            bfrag bf = *(const bfrag*)&W0p[(size_t)(((nt * 4) + ks) * 64 + lane) * 8];
            acc[nt] = __builtin_amdgcn_mfma_f32_16x16x32_bf16(af, bf, acc[nt], 0, 0, 0);
        }
    }
#pragma unroll
    for (int nt = 0; nt < 8; ++nt)
#pragma unroll
        for (int reg = 0; reg < 4; ++reg)
            hs[crow + reg][nt * 16 + ccol] = f2bf(fmaxf(acc[nt][reg] + bia0[nt], 0.f));
    __syncthreads();

#pragma unroll
    for (int nt = 0; nt < 8; ++nt) acc[nt] = (ffrag)0.0f;
#pragma unroll
    for (int ks = 0; ks < 4; ++ks) {
        bfrag af = *(const bfrag*)&hs[mrow][ks * 32 + koff];
#pragma unroll
        for (int nt = 0; nt < 8; ++nt) {
            bfrag bf = *(const bfrag*)&W1p[(size_t)(((nt * 4) + ks) * 64 + lane) * 8];
            acc[nt] = __builtin_amdgcn_mfma_f32_16x16x32_bf16(af, bf, acc[nt], 0, 0, 0);
        }
    }
    __syncthreads();
#pragma unroll
    for (int nt = 0; nt < 8; ++nt)
#pragma unroll
        for (int reg = 0; reg < 4; ++reg)
            hs[crow + reg][nt * 16 + ccol] = f2bf(fmaxf(acc[nt][reg] + bia1[nt], 0.f));
    __syncthreads();

    // copy-out with bf16 -> fp8 e4m3 conversion (row = 128 B)
#pragma unroll
    for (int it = 0; it < 8; ++it) {
        int fi = it * 256 + tid;
        int rr = fi >> 5, uc = fi & 31;
        if (rr < rows) {
            unsigned long long pk8 = *(unsigned long long*)&hs[rr][uc * 4];
            float f0 = bf2f((unsigned int)(pk8 & 0xFFFFu));
            float f1 = bf2f((unsigned int)((pk8 >> 16) & 0xFFFFu));
            float f2 = bf2f((unsigned int)((pk8 >> 32) & 0xFFFFu));
            float f3 = bf2f((unsigned int)((pk8 >> 48) & 0xFFFFu));
            int o = __builtin_amdgcn_cvt_pk_fp8_f32(f0, f1, 0, false);
            o = __builtin_amdgcn_cvt_pk_fp8_f32(f2, f3, o, true);
            *(int*)&x[(size_t)(brow + rr) * LAT + uc * 4] = o;
        }
    }
}

// ---------------- MLP steps 2,3 — inv_sqrt(sender_deg) in epilogue, fp8 x out ----------------

__global__ __launch_bounds__(256) void k_mlp2(
    const unsigned short* __restrict__ h,
    const unsigned short* __restrict__ W0p, const unsigned short* __restrict__ W1p,
    const float* __restrict__ b0, const float* __restrict__ b1,
    const unsigned int* __restrict__ cnt,
    unsigned char* __restrict__ x, int M)
{
    __shared__ unsigned short hs[64][HSTR];
    int brow = blockIdx.x * 64;
    int tid = threadIdx.x;
    int rows = M - brow; if (rows > 64) rows = 64;

#pragma unroll
    for (int it = 0; it < 8; ++it) {
        int fi = it * 256 + tid;
        int rr = fi >> 5, cc = (fi & 31) << 2;
        if (rr < rows)
            *(unsigned long long*)&hs[rr][cc] =
                *(const unsigned long long*)&h[(size_t)(brow + rr) * LAT + cc];
    }
    __syncthreads();

    int w = tid >> 6, lane = tid & 63;
    int mrow = w * 16 + (lane & 15);
    int koff = (lane >> 4) * 8;
    int ccol = lane & 15;
    int crow = w * 16 + (lane >> 4) * 4;

    float bia0[8], bia1[8];
#pragma unroll
    for (int nt = 0; nt < 8; ++nt) { bia0[nt] = b0[nt * 16 + ccol]; bia1[nt] = b1[nt * 16 + ccol]; }
    float iv[4];
#pragma unroll
    for (int reg = 0; reg < 4; ++reg) {
        int rw = brow + crow + reg;
        unsigned int ds = cnt[rw < NN ? rw : NN - 1] & 0xFFFFu;
        iv[reg] = rsqrtf((float)(ds > 1 ? ds : 1));
    }

    ffrag acc[8];
#pragma unroll
    for (int nt = 0; nt < 8; ++nt) acc[nt] = (ffrag)0.0f;
#pragma unroll
    for (int ks = 0; ks < 4; ++ks) {
        bfrag af = *(const bfrag*)&hs[mrow][ks * 32 + koff];
#pragma unroll
        for (int nt = 0; nt < 8; ++nt) {
            bfrag bf = *(const bfrag*)&W0p[(size_t)(((nt * 4) + ks) * 64 + lane) * 8];
            acc[nt] = __builtin_amdgcn_mfma_f32_16x16x32_bf16(af, bf, acc[nt], 0, 0, 0);
        }
    }
#pragma unroll
    for (int nt = 0; nt < 8; ++nt)
#pragma unroll
        for (int reg = 0; reg < 4; ++reg)
            hs[crow + reg][nt * 16 + ccol] = f2bf(fmaxf(acc[nt][reg] + bia0[nt], 0.f));
    __syncthreads();

#pragma unroll
    for (int nt = 0; nt < 8; ++nt) acc[nt] = (ffrag)0.0f;
#pragma unroll
    for (int ks = 0; ks < 4; ++ks) {
        bfrag af = *(const bfrag*)&hs[mrow][ks * 32 + koff];
#pragma unroll
        for (int nt = 0; nt < 8; ++nt) {
            bfrag bf = *(const bfrag*)&W1p[(size_t)(((nt * 4) + ks) * 64 + lane) * 8];
            acc[nt] = __builtin_amdgcn_mfma_f32_16x16x32_bf16(af, bf, acc[nt], 0, 0, 0);
        }
    }
    __syncthreads();
#pragma unroll
    for (int nt = 0; nt < 8; ++nt)
#pragma unroll
        for (int reg = 0; reg < 4; ++reg)
            hs[crow + reg][nt * 16 + ccol] =
                f2bf(fmaxf(acc[nt][reg] + bia1[nt], 0.f) * iv[reg]);
    __syncthreads();

#pragma unroll
    for (int it = 0; it < 8; ++it) {
        int fi = it * 256 + tid;
        int rr = fi >> 5, uc = fi & 31;
        if (rr < rows) {
            unsigned long long pk8 = *(unsigned long long*)&hs[rr][uc * 4];
            float f0 = bf2f((unsigned int)(pk8 & 0xFFFFu));
            float f1 = bf2f((unsigned int)((pk8 >> 16) & 0xFFFFu));
            float f2 = bf2f((unsigned int)((pk8 >> 32) & 0xFFFFu));
            float f3 = bf2f((unsigned int)((pk8 >> 48) & 0xFFFFu));
            int o = __builtin_amdgcn_cvt_pk_fp8_f32(f0, f1, 0, false);
            o = __builtin_amdgcn_cvt_pk_fp8_f32(f2, f3, o, true);
            *(int*)&x[(size_t)(brow + rr) * LAT + uc * 4] = o;
        }
    }
}

// ---------------- aggregate + skip + LayerNorm (+ fused decode) ----------------
// TWO receivers per wave: half-waves of 32 lanes, lane = 4 fp8 channels (dword).
// One gather instruction fetches rows for 2 edges -> ~40% fewer gather instrs.
// Always-weighted loop: w staged as inv_s (mode 0) or 1.0 (modes 1/2), 0 beyond
// degree; indices zero-clamped so inactive edges read row 0 harmlessly.

__global__ __launch_bounds__(256) void k_agg(
    const unsigned char* __restrict__ x, unsigned short* __restrict__ h,
    const float* __restrict__ nodes, const float* __restrict__ We,
    const float* __restrict__ be,
    const unsigned int* __restrict__ cnt, const unsigned short* __restrict__ slot,
    const float* __restrict__ gamma, const float* __restrict__ beta,
    const float* __restrict__ Wd, const float* __restrict__ bd,
    float* __restrict__ outd, int mode)
{
    int tid = threadIdx.x;
    int wid = tid >> 6;
    int lane = tid & 63;
    int half = lane >> 5;
    int li = lane & 31;
    int r = blockIdx.x * 8 + wid * 2 + half;          // 6250 blocks * 8 = 50000 exact
    int cb = li * 4;                                   // this lane's 4 channels

    int ct = (int)(cnt[r] >> 16);
    float ir = rsqrtf((float)(ct > 1 ? ct : 1));
    int c = ct > CSR_W ? CSR_W : ct;

    // stage 64 slots per receiver in 2 regs per lane (32 lanes/receiver)
    int idx0 = 0, idx1 = 0;
    float wt0 = 0.f, wt1 = 0.f;
    if (li < c)      idx0 = (int)slot[(size_t)r * CSR_W + li];
    if (32 + li < c) idx1 = (int)slot[(size_t)r * CSR_W + 32 + li];
    if (mode == 0) {
        if (li < c)      { unsigned int d = cnt[idx0] & 0xFFFFu; wt0 = rsqrtf((float)(d > 1 ? d : 1)); }
        if (32 + li < c) { unsigned int d = cnt[idx1] & 0xFFFFu; wt1 = rsqrtf((float)(d > 1 ? d : 1)); }
    } else {
        wt0 = (li < c) ? 1.f : 0.f;
        wt1 = (32 + li < c) ? 1.f : 0.f;
    }

    int cother = __shfl_xor(c, 32);
    int cmax = c > cother ? c : cother;

    float ac[4][4];
#pragma unroll
    for (int k = 0; k < 4; ++k)
#pragma unroll
        for (int j = 0; j < 4; ++j) ac[k][j] = 0.f;

    int base = half * 32;
    for (int e = 0; e < cmax; e += 4) {
#pragma unroll
        for (int k = 0; k < 4; ++k) {
            int ee = e + k;                    // wave-uniform
            int srcl = base + (ee & 31);
            int idx  = __shfl(ee < 32 ? idx0 : idx1, srcl);
            float wv = __shfl(ee < 32 ? wt0 : wt1, srcl);
            unsigned int v = *(const unsigned int*)&x[(size_t)idx * LAT + cb];
            f32x2 dlo = __builtin_amdgcn_cvt_pk_f32_fp8((int)v, false);
            f32x2 dhi = __builtin_amdgcn_cvt_pk_f32_fp8((int)v, true);
            ac[k][0] += dlo.x * wv; ac[k][1] += dlo.y * wv;
            ac[k][2] += dhi.x * wv; ac[k][3] += dhi.y * wv;
        }
    }

    float sagg[4];
#pragma unroll
    for (int j = 0; j < 4; ++j)
        sagg[j] = ((ac[0][j] + ac[1][j]) + (ac[2][j] + ac[3][j])) * ir;

    float val[4];
    if (mode == 0) {
        float nk[IN_F];
#pragma unroll
        for (int k = 0; k < IN_F; ++k) nk[k] = nodes[(size_t)r * IN_F + k];
#pragma unroll
        for (int j = 0; j < 4; ++j) {
            float o = be[cb + j];
#pragma unroll
            for (int k = 0; k < IN_F; ++k) o += nk[k] * We[k * LAT + cb + j];
            val[j] = o + sagg[j];
        }
    } else {
        uint2 hv = *(const uint2*)&h[(size_t)r * LAT + cb];
        val[0] = bf2f(hv.x & 0xFFFFu) + sagg[0];
        val[1] = bf2f(hv.x >> 16)     + sagg[1];
        val[2] = bf2f(hv.y & 0xFFFFu) + sagg[2];
        val[3] = bf2f(hv.y >> 16)     + sagg[3];
    }

    float sum = 0.f, sq = 0.f;
#pragma unroll
    for (int j = 0; j < 4; ++j) { sum += val[j]; sq += val[j] * val[j]; }
#pragma unroll
    for (int m = 1; m <= 16; m <<= 1) {      // reduce within 32-lane half
        sum += __shfl_xor(sum, m);
        sq  += __shfl_xor(sq, m);
    }
    float mu = sum * (1.f / LAT);
    float rs = rsqrtf(sq * (1.f / LAT) - mu * mu + 1e-6f);

    float o[4];
#pragma unroll
    for (int j = 0; j < 4; ++j)
        o[j] = (val[j] - mu) * rs * gamma[cb + j] + beta[cb + j];

    if (mode < 2) {
        uint2 st;
        st.x = (unsigned int)f2bf(o[0]) | ((unsigned int)f2bf(o[1]) << 16);
        st.y = (unsigned int)f2bf(o[2]) | ((unsigned int)f2bf(o[3]) << 16);
        *(uint2*)&h[(size_t)r * LAT + cb] = st;
    } else {
#pragma unroll
        for (int f = 0; f < IN_F; ++f) {
            float pv = 0.f;
#pragma unroll
            for (int j = 0; j < 4; ++j) pv += o[j] * Wd[(cb + j) * IN_F + f];
#pragma unroll
            for (int m = 1; m <= 16; m <<= 1) pv += __shfl_xor(pv, m);
            if (li == 0) outd[(size_t)r * IN_F + f] = pv + bd[f];
        }
    }
}

// ---------------- host ----------------

extern "C" void kernel_launch(void* const* d_in, const int* in_sizes, int n_in,
                              void* d_out, int out_size, void* d_ws, size_t ws_size,
                              hipStream_t stream)
{
    const float* nodes   = (const float*)d_in[0];
    const int*   senders = (const int*)d_in[1];
    const int*   recvs   = (const int*)d_in[2];
    const float* W_embed = (const float*)d_in[3];
    const float* b_embed = (const float*)d_in[4];
    const float* mlp_W   = (const float*)d_in[5];
    const float* mlp_b   = (const float*)d_in[6];
    const float* ln_s    = (const float*)d_in[7];
    const float* ln_b    = (const float*)d_in[8];
    const float* W_dec   = (const float*)d_in[9];
    const float* b_dec   = (const float*)d_in[10];
    float* out = (float*)d_out;

    char* p = (char*)d_ws;
    auto alloc = [&](size_t bytes) -> char* {
        char* q = p; p += (bytes + 255) & ~(size_t)255; return q;
    };
    unsigned short* h    = (unsigned short*)alloc((size_t)NN * LAT * 2);
    unsigned char*  x    = (unsigned char*)alloc((size_t)NN * LAT);
    unsigned short* Wp   = (unsigned short*)alloc((size_t)6 * LAT * LAT * 2);
    unsigned int* cnt    = (unsigned int*)alloc((size_t)NN * 4);
    unsigned short* slot = (unsigned short*)alloc((size_t)NN * CSR_W * 2);

    k_prep<<<(NN + 255) / 256, 256, 0, stream>>>(mlp_W, Wp, cnt);

    int build_blocks = NXCD * ((NE + 255) / 256);        // 8 * 2344 = 18752
    int mlp_blocks   = (NN + 63) / 64;                   // 782
    int agg_blocks   = (NN + 7) / 8;                     // 6250

    const float* b0 = mlp_b;
    k_fused1<<<build_blocks + mlp_blocks, 256, 0, stream>>>(
        senders, recvs, cnt, slot, nodes, W_embed, b_embed,
        Wp, Wp + (size_t)LAT * LAT, b0, b0 + LAT, x, build_blocks);

    // step 1 (x unscaled -> weighted gather; skip = inline embed)
    k_agg<<<agg_blocks, 256, 0, stream>>>(
        x, h, nodes, W_embed, b_embed, cnt, slot,
        ln_s, ln_b, nullptr, nullptr, nullptr, 0);

    // step 2
    k_mlp2<<<mlp_blocks, 256, 0, stream>>>(
        h, Wp + (size_t)2 * LAT * LAT, Wp + (size_t)3 * LAT * LAT,
        b0 + 2 * LAT, b0 + 3 * LAT, cnt, x, NN);
    k_agg<<<agg_blocks, 256, 0, stream>>>(
        x, h, nodes, W_embed, b_embed, cnt, slot,
        ln_s + LAT, ln_b + LAT, nullptr, nullptr, nullptr, 1);

    // step 3 (+ fused decode)
    k_mlp2<<<mlp_blocks, 256, 0, stream>>>(
        h, Wp + (size_t)4 * LAT * LAT, Wp + (size_t)5 * LAT * LAT,
        b0 + 4 * LAT, b0 + 5 * LAT, cnt, x, NN);
    k_agg<<<agg_blocks, 256, 0, stream>>>(
        x, h, nodes, W_embed, b_embed, cnt, slot,
        ln_s + 2 * LAT, ln_b + 2 * LAT, W_dec, b_dec, out, 2);
}